// Round 9
// baseline (320.593 us; speedup 1.0000x reference)
//
#include <hip/hip_runtime.h>

#define N_NODES 100000
#define NBIN_D  391           // dst bins of 256 nodes (391*256 = 100096)
#define NW      4             // src windows: src>>15
#define NBINS_TOT (NW * NBIN_D)   // 1564 sort bins, w-major
#define NCHUNK  512
#define CAP     8192          // LDS stage capacity (mean bin = 4096 edges)

// ---------------- dtype detection (int64 vs int32 edge_index) ---------------
// edge values < 2^31. If int64 LE, every odd 32-bit word is 0.
__global__ void detect_i64_kernel(const unsigned int* __restrict__ e,
                                  unsigned int* __restrict__ flag) {
    int i = blockIdx.x * blockDim.x + threadIdx.x;  // 0..2047
    unsigned int v = e[2 * i + 1];
    if (v != 0u) atomicOr(flag, 1u);
}

// ---------------- pad x (N x 5 f32) -> fp32x8 (32B rows) --------------------
__global__ void pad_x_kernel(const float* __restrict__ x, float4* __restrict__ xp, int N) {
    int n = blockIdx.x * blockDim.x + threadIdx.x;
    if (n >= N) return;
    const float* p = x + (long long)n * 5;
    xp[n * 2]     = make_float4(p[0], p[1], p[2], p[3]);
    xp[n * 2 + 1] = make_float4(p[4], 0.f, 0.f, 0.f);
}

// ---------------- pass 1a: per-chunk histogram over (w, dst_bin) ------------
__global__ void count_kernel(const void* __restrict__ eidx,
                             const unsigned int* __restrict__ flag,
                             int* __restrict__ hist, int E) {
    __shared__ int lh[NBINS_TOT];
    int tid = threadIdx.x, c = blockIdx.x;
    for (int i = tid; i < NBINS_TOT; i += blockDim.x) lh[i] = 0;
    __syncthreads();
    int per = (E + NCHUNK - 1) / NCHUNK;
    int e0 = c * per, e1 = min(E, e0 + per);
    unsigned int is32 = *flag;
    for (int e = e0 + tid; e < e1; e += blockDim.x) {
        int s, d;
        if (is32) {
            const int* p = (const int*)eidx; s = p[e]; d = p[E + e];
        } else {
            const long long* p = (const long long*)eidx; s = (int)p[e]; d = (int)p[E + e];
        }
        atomicAdd(&lh[(s >> 15) * NBIN_D + (d >> 8)], 1);
    }
    __syncthreads();
    for (int i = tid; i < NBINS_TOT; i += blockDim.x) hist[c * NBINS_TOT + i] = lh[i];
}

// ---------------- pass 1b: per-bin column scan (1 wave per bin) -------------
__global__ void scan1_kernel(const int* __restrict__ hist,
                             int* __restrict__ off_rel,
                             int* __restrict__ totals) {
    int gtid = blockIdx.x * blockDim.x + threadIdx.x;
    int b = gtid >> 6;
    int lane = threadIdx.x & 63;
    if (b >= NBINS_TOT) return;
    int carry = 0;
    for (int k = 0; k < NCHUNK; k += 64) {
        int v = hist[(k + lane) * NBINS_TOT + b];
        int sc = v;
        for (int off = 1; off < 64; off <<= 1) {
            int t = __shfl_up(sc, off);
            if (lane >= off) sc += t;
        }
        off_rel[(k + lane) * NBINS_TOT + b] = carry + sc - v;   // exclusive
        carry += __shfl(sc, 63);
    }
    if (lane == 0) totals[b] = carry;
}

// ---------------- pass 1c: scan bin totals -> bin_start (2 per thread) ------
__global__ void scan2_kernel(const int* __restrict__ totals,
                             int* __restrict__ bin_start) {
    __shared__ int buf[1024];
    int t = threadIdx.x;
    int i0 = 2 * t, i1 = 2 * t + 1;
    int v0 = (i0 < NBINS_TOT) ? totals[i0] : 0;
    int v1 = (i1 < NBINS_TOT) ? totals[i1] : 0;
    int s = v0 + v1;
    buf[t] = s;
    __syncthreads();
    for (int off = 1; off < 1024; off <<= 1) {
        int v = (t >= off) ? buf[t - off] : 0;
        __syncthreads();
        buf[t] += v;
        __syncthreads();
    }
    int excl = buf[t] - s;
    if (t == 0) bin_start[0] = 0;
    if (i0 < NBINS_TOT) bin_start[i0 + 1] = excl + v0;
    if (i1 < NBINS_TOT) bin_start[i1 + 1] = excl + v0 + v1;
}

// ---------------- pass 1d: scatter edges into (w, dst_bin) order ------------
// packed edge word: (dl << 17) | src   (dl = dst & 255, src < 2^17)
__global__ void scatter1_kernel(const void* __restrict__ eidx,
                                const unsigned int* __restrict__ flag,
                                const int* __restrict__ off_rel,
                                const int* __restrict__ bin_start,
                                unsigned int* __restrict__ sorted1, int E) {
    __shared__ int lcnt[NBINS_TOT];
    __shared__ int lbase[NBINS_TOT];
    int tid = threadIdx.x, c = blockIdx.x;
    for (int i = tid; i < NBINS_TOT; i += blockDim.x) {
        lcnt[i] = 0;
        lbase[i] = bin_start[i] + off_rel[c * NBINS_TOT + i];
    }
    __syncthreads();
    int per = (E + NCHUNK - 1) / NCHUNK;
    int e0 = c * per, e1 = min(E, e0 + per);
    unsigned int is32 = *flag;
    for (int e = e0 + tid; e < e1; e += blockDim.x) {
        int s, d;
        if (is32) {
            const int* p = (const int*)eidx; s = p[e]; d = p[E + e];
        } else {
            const long long* p = (const long long*)eidx; s = (int)p[e]; d = (int)p[E + e];
        }
        int b = (s >> 15) * NBIN_D + (d >> 8);
        int dl = d & 255;
        int pos = lbase[b] + atomicAdd(&lcnt[b], 1);
        sorted1[pos] = ((unsigned int)dl << 17) | (unsigned int)s;
    }
}

// ---------------- pass 2: per-(w,bin) LDS counting sort -> window CSR -------
// rp[w*(N+1) + n] .. rp[w*(N+1) + n + 1] = node n's edges in window w.
// Sorted output staged in LDS, streamed out coalesced.
__global__ __launch_bounds__(512) void dlsort_kernel(
    const unsigned int* __restrict__ sorted1,
    const int* __restrict__ bin_start,
    unsigned int* __restrict__ sorted2,
    int* __restrict__ rp, int N) {
    __shared__ int hist[256];
    __shared__ int pfx[256];
    __shared__ int offc[256];
    __shared__ unsigned int stage[CAP];
    int tid = threadIdx.x, b = blockIdx.x;
    int w = b / NBIN_D, dbin = b - w * NBIN_D;
    int bs = bin_start[b], be = bin_start[b + 1];
    int cnt = be - bs;
    if (tid < 256) hist[tid] = 0;
    __syncthreads();
    for (int e = bs + tid; e < be; e += 512)
        atomicAdd(&hist[(sorted1[e] >> 17) & 255], 1);
    __syncthreads();
    if (tid < 256) pfx[tid] = hist[tid];
    __syncthreads();
    for (int off = 1; off < 256; off <<= 1) {
        int v = (tid < 256 && tid >= off) ? pfx[tid - off] : 0;
        __syncthreads();
        if (tid < 256) pfx[tid] += v;
        __syncthreads();
    }
    if (tid < 256) {
        int excl = pfx[tid] - hist[tid];
        offc[tid] = excl;
        int node = dbin * 256 + tid;
        if (node <= N) rp[w * (N + 1) + node] = bs + excl;
    }
    __syncthreads();
    if (cnt <= CAP) {
        for (int e = bs + tid; e < be; e += 512) {
            unsigned int wd = sorted1[e];
            int pos = atomicAdd(&offc[(wd >> 17) & 255], 1);
            stage[pos] = wd;
        }
        __syncthreads();
        for (int i = tid; i < cnt; i += 512) sorted2[bs + i] = stage[i];
    } else {
        // overflow slow path (statistically unreachable for uniform dst)
        for (int e = bs + tid; e < be; e += 512) {
            unsigned int wd = sorted1[e];
            int pos = bs + atomicAdd(&offc[(wd >> 17) & 255], 1);
            sorted2[pos] = wd;
        }
    }
}

// ---------------- aggregation F=5 (layer 1): lane = (node, window) ----------
__global__ __launch_bounds__(256) void agg5_csr(
    const unsigned int* __restrict__ sorted2, const int* __restrict__ rp,
    const float4* __restrict__ xp, float* __restrict__ agg, int N) {
    int t = blockIdx.x * 256 + threadIdx.x;
    int n = t >> 2, w = t & 3;
    if (n >= N) return;
    int e0 = rp[w * (N + 1) + n], e1 = rp[w * (N + 1) + n + 1];
    float a0 = 0, a1 = 0, a2 = 0, a3 = 0, a4 = 0;
    int e = e0;
    for (; e + 1 < e1; e += 2) {
        int s0 = (int)(sorted2[e] & 0x1FFFF), s1 = (int)(sorted2[e + 1] & 0x1FFFF);
        float4 v0 = xp[s0 * 2], w0 = xp[s0 * 2 + 1];
        float4 v1 = xp[s1 * 2], w1 = xp[s1 * 2 + 1];
        a0 += v0.x; a1 += v0.y; a2 += v0.z; a3 += v0.w; a4 += w0.x;
        a0 += v1.x; a1 += v1.y; a2 += v1.z; a3 += v1.w; a4 += w1.x;
    }
    if (e < e1) {
        int s0 = (int)(sorted2[e] & 0x1FFFF);
        float4 v0 = xp[s0 * 2], w0 = xp[s0 * 2 + 1];
        a0 += v0.x; a1 += v0.y; a2 += v0.z; a3 += v0.w; a4 += w0.x;
    }
    // reduce across the 4 window lanes
    a0 += __shfl_xor(a0, 1); a1 += __shfl_xor(a1, 1); a2 += __shfl_xor(a2, 1);
    a3 += __shfl_xor(a3, 1); a4 += __shfl_xor(a4, 1);
    a0 += __shfl_xor(a0, 2); a1 += __shfl_xor(a1, 2); a2 += __shfl_xor(a2, 2);
    a3 += __shfl_xor(a3, 2); a4 += __shfl_xor(a4, 2);
    if (w == 0) {
        float* o = agg + (long long)n * 5;
        o[0] = a0; o[1] = a1; o[2] = a2; o[3] = a3; o[4] = a4;
    }
}

// ---------------- aggregation F=16 (layer 2): lane = (node, window) ---------
__global__ __launch_bounds__(256) void agg16_csr(
    const unsigned int* __restrict__ sorted2, const int* __restrict__ rp,
    const float4* __restrict__ h, float* __restrict__ agg, int N) {
    int t = blockIdx.x * 256 + threadIdx.x;
    int n = t >> 2, w = t & 3;
    if (n >= N) return;
    int e0 = rp[w * (N + 1) + n], e1 = rp[w * (N + 1) + n + 1];
    float a0 = 0, a1 = 0, a2 = 0, a3 = 0, a4 = 0, a5 = 0, a6 = 0, a7 = 0;
    float b0 = 0, b1 = 0, b2 = 0, b3 = 0, b4 = 0, b5 = 0, b6 = 0, b7 = 0;
    int e = e0;
    for (; e + 1 < e1; e += 2) {
        int s0 = (int)(sorted2[e] & 0x1FFFF), s1 = (int)(sorted2[e + 1] & 0x1FFFF);
        float4 p0 = h[s0 * 4 + 0], p1 = h[s0 * 4 + 1], p2 = h[s0 * 4 + 2], p3 = h[s0 * 4 + 3];
        float4 q0 = h[s1 * 4 + 0], q1 = h[s1 * 4 + 1], q2 = h[s1 * 4 + 2], q3 = h[s1 * 4 + 3];
        a0 += p0.x; a1 += p0.y; a2 += p0.z; a3 += p0.w;
        a4 += p1.x; a5 += p1.y; a6 += p1.z; a7 += p1.w;
        b0 += p2.x; b1 += p2.y; b2 += p2.z; b3 += p2.w;
        b4 += p3.x; b5 += p3.y; b6 += p3.z; b7 += p3.w;
        a0 += q0.x; a1 += q0.y; a2 += q0.z; a3 += q0.w;
        a4 += q1.x; a5 += q1.y; a6 += q1.z; a7 += q1.w;
        b0 += q2.x; b1 += q2.y; b2 += q2.z; b3 += q2.w;
        b4 += q3.x; b5 += q3.y; b6 += q3.z; b7 += q3.w;
    }
    if (e < e1) {
        int s0 = (int)(sorted2[e] & 0x1FFFF);
        float4 p0 = h[s0 * 4 + 0], p1 = h[s0 * 4 + 1], p2 = h[s0 * 4 + 2], p3 = h[s0 * 4 + 3];
        a0 += p0.x; a1 += p0.y; a2 += p0.z; a3 += p0.w;
        a4 += p1.x; a5 += p1.y; a6 += p1.z; a7 += p1.w;
        b0 += p2.x; b1 += p2.y; b2 += p2.z; b3 += p2.w;
        b4 += p3.x; b5 += p3.y; b6 += p3.z; b7 += p3.w;
    }
    // reduce across the 4 window lanes
    a0 += __shfl_xor(a0, 1); a1 += __shfl_xor(a1, 1); a2 += __shfl_xor(a2, 1); a3 += __shfl_xor(a3, 1);
    a4 += __shfl_xor(a4, 1); a5 += __shfl_xor(a5, 1); a6 += __shfl_xor(a6, 1); a7 += __shfl_xor(a7, 1);
    b0 += __shfl_xor(b0, 1); b1 += __shfl_xor(b1, 1); b2 += __shfl_xor(b2, 1); b3 += __shfl_xor(b3, 1);
    b4 += __shfl_xor(b4, 1); b5 += __shfl_xor(b5, 1); b6 += __shfl_xor(b6, 1); b7 += __shfl_xor(b7, 1);
    a0 += __shfl_xor(a0, 2); a1 += __shfl_xor(a1, 2); a2 += __shfl_xor(a2, 2); a3 += __shfl_xor(a3, 2);
    a4 += __shfl_xor(a4, 2); a5 += __shfl_xor(a5, 2); a6 += __shfl_xor(a6, 2); a7 += __shfl_xor(a7, 2);
    b0 += __shfl_xor(b0, 2); b1 += __shfl_xor(b1, 2); b2 += __shfl_xor(b2, 2); b3 += __shfl_xor(b3, 2);
    b4 += __shfl_xor(b4, 2); b5 += __shfl_xor(b5, 2); b6 += __shfl_xor(b6, 2); b7 += __shfl_xor(b7, 2);
    if (w == 0) {
        float4* o = (float4*)(agg + (long long)n * 16);
        o[0] = make_float4(a0, a1, a2, a3);
        o[1] = make_float4(a4, a5, a6, a7);
        o[2] = make_float4(b0, b1, b2, b3);
        o[3] = make_float4(b4, b5, b6, b7);
    }
}

// ------------- MLP1: h = relu((x+agg1)@W1a+b1a)@W1b+b1b  (fp32 h) -----------
__global__ void mlp1_kernel(const float* __restrict__ x,
                            const float* __restrict__ agg,
                            const float* __restrict__ W1, const float* __restrict__ b1,
                            const float* __restrict__ W2, const float* __restrict__ b2,
                            float* __restrict__ h, int N) {
    int n = blockIdx.x * blockDim.x + threadIdx.x;
    if (n >= N) return;
    float in[5];
#pragma unroll
    for (int f = 0; f < 5; ++f)
        in[f] = x[(long long)n * 5 + f] + agg[(long long)n * 5 + f];
    float hid[16];
#pragma unroll
    for (int j = 0; j < 16; ++j) {
        float acc = b1[j];
#pragma unroll
        for (int f = 0; f < 5; ++f) acc = fmaf(in[f], W1[f * 16 + j], acc);
        hid[j] = fmaxf(acc, 0.0f);
    }
    float4* op = (float4*)(h + (long long)n * 16);
#pragma unroll
    for (int jq = 0; jq < 4; ++jq) {
        float4 v;
        float acc;
        acc = b2[jq * 4 + 0];
#pragma unroll
        for (int k = 0; k < 16; ++k) acc = fmaf(hid[k], W2[k * 16 + jq * 4 + 0], acc);
        v.x = acc;
        acc = b2[jq * 4 + 1];
#pragma unroll
        for (int k = 0; k < 16; ++k) acc = fmaf(hid[k], W2[k * 16 + jq * 4 + 1], acc);
        v.y = acc;
        acc = b2[jq * 4 + 2];
#pragma unroll
        for (int k = 0; k < 16; ++k) acc = fmaf(hid[k], W2[k * 16 + jq * 4 + 2], acc);
        v.z = acc;
        acc = b2[jq * 4 + 3];
#pragma unroll
        for (int k = 0; k < 16; ++k) acc = fmaf(hid[k], W2[k * 16 + jq * 4 + 3], acc);
        v.w = acc;
        op[jq] = v;
    }
}

// ------------- MLP2: out = relu((h+agg2)@W2a+b2a)@W2b+b2b -------------------
__global__ void mlp2_kernel(const float* __restrict__ h,
                            const float* __restrict__ agg,
                            const float* __restrict__ W1, const float* __restrict__ b1,
                            const float* __restrict__ W2, const float* __restrict__ b2,
                            float* __restrict__ out, int N) {
    int n = blockIdx.x * blockDim.x + threadIdx.x;
    if (n >= N) return;
    float in[16];
    const float4* hp = (const float4*)(h + (long long)n * 16);
    const float4* ap = (const float4*)(agg + (long long)n * 16);
#pragma unroll
    for (int qq = 0; qq < 4; ++qq) {
        float4 a = hp[qq], b = ap[qq];
        in[qq * 4 + 0] = a.x + b.x; in[qq * 4 + 1] = a.y + b.y;
        in[qq * 4 + 2] = a.z + b.z; in[qq * 4 + 3] = a.w + b.w;
    }
    float hid[16];
#pragma unroll
    for (int j = 0; j < 16; ++j) {
        float acc = b1[j];
#pragma unroll
        for (int f = 0; f < 16; ++f) acc = fmaf(in[f], W1[f * 16 + j], acc);
        hid[j] = fmaxf(acc, 0.0f);
    }
    float4* op = (float4*)(out + (long long)n * 16);
#pragma unroll
    for (int jq = 0; jq < 4; ++jq) {
        float4 v;
        float acc;
        acc = b2[jq * 4 + 0];
#pragma unroll
        for (int k = 0; k < 16; ++k) acc = fmaf(hid[k], W2[k * 16 + jq * 4 + 0], acc);
        v.x = acc;
        acc = b2[jq * 4 + 1];
#pragma unroll
        for (int k = 0; k < 16; ++k) acc = fmaf(hid[k], W2[k * 16 + jq * 4 + 1], acc);
        v.y = acc;
        acc = b2[jq * 4 + 2];
#pragma unroll
        for (int k = 0; k < 16; ++k) acc = fmaf(hid[k], W2[k * 16 + jq * 4 + 2], acc);
        v.z = acc;
        acc = b2[jq * 4 + 3];
#pragma unroll
        for (int k = 0; k < 16; ++k) acc = fmaf(hid[k], W2[k * 16 + jq * 4 + 3], acc);
        v.w = acc;
        op[jq] = v;
    }
}

// ---------- fallback path (ws too small): global atomics, fp32 --------------
__device__ __forceinline__ void load_edge(const void* eidx, unsigned int is32,
                                          int i, int E, int& s, int& d) {
    if (is32 == 0u) {
        const long long* p = (const long long*)eidx;
        s = (int)p[i]; d = (int)p[E + i];
    } else {
        const int* p = (const int*)eidx;
        s = p[i]; d = p[E + i];
    }
}

__global__ void scatter_f5_kernel(const void* __restrict__ eidx,
                                  const unsigned int* __restrict__ flag,
                                  const float* __restrict__ x,
                                  float* __restrict__ agg, int E) {
    int i = blockIdx.x * blockDim.x + threadIdx.x;
    if (i >= E) return;
    int s, d; load_edge(eidx, *flag, i, E, s, d);
    const float* xs = x + (long long)s * 5;
    float* a = agg + (long long)d * 5;
#pragma unroll
    for (int f = 0; f < 5; ++f) atomicAdd(&a[f], xs[f]);
}

__global__ void scatter_f16_kernel(const void* __restrict__ eidx,
                                   const unsigned int* __restrict__ flag,
                                   const float* __restrict__ h,
                                   float* __restrict__ agg, int E) {
    int i = blockIdx.x * blockDim.x + threadIdx.x;
    if (i >= E) return;
    int s, d; load_edge(eidx, *flag, i, E, s, d);
    const float* hs = h + (long long)s * 16;
    float* a = agg + (long long)d * 16;
#pragma unroll
    for (int f = 0; f < 16; ++f) atomicAdd(&a[f], hs[f]);
}

extern "C" void kernel_launch(void* const* d_in, const int* in_sizes, int n_in,
                              void* d_out, int out_size, void* d_ws, size_t ws_size,
                              hipStream_t stream) {
    const float* x    = (const float*)d_in[0];
    const void*  eidx = d_in[1];
    const float* W1a  = (const float*)d_in[2];
    const float* b1a  = (const float*)d_in[3];
    const float* W1b  = (const float*)d_in[4];
    const float* b1b  = (const float*)d_in[5];
    const float* W2a  = (const float*)d_in[6];
    const float* b2a  = (const float*)d_in[7];
    const float* W2b  = (const float*)d_in[8];
    const float* b2b  = (const float*)d_in[9];
    float* out = (float*)d_out;

    const int E = in_sizes[1] / 2;
    const int N = N_NODES;

    char* ws = (char*)d_ws;
    auto align256 = [](size_t v) { return (v + 255) & ~(size_t)255; };
    const size_t hist_bytes = (size_t)NCHUNK * NBINS_TOT * 4;          // 3.2 MB

    const size_t off_flag     = 0;
    const size_t off_binstart = 256;                                    // 1565*4
    const size_t off_totals   = align256(off_binstart + (NBINS_TOT + 1) * 4);
    const size_t off_rp       = align256(off_totals + NBINS_TOT * 4);   // NW*(N+1)*4
    const size_t off_hist     = align256(off_rp + (size_t)NW * (N + 1) * 4);
    const size_t off_offrel   = align256(off_hist + hist_bytes);
    const size_t off_xp       = align256(off_offrel + hist_bytes);      // N*32 fp32x8
    const size_t off_sorted1  = align256(off_xp + (size_t)N * 32);      // E*4
    const size_t off_sorted2  = align256(off_sorted1 + (size_t)E * 4);  // E*4
    const size_t need         = off_sorted2 + (size_t)E * 4;

    // agg1/agg2/h alias the dead sorted1 region after dlsort:
    //   agg1 @ +0        (N*5*4  = 2.0 MB)
    //   agg2 @ +2 MiB    (N*16*4 = 6.4 MB)
    //   h    @ +9 MiB    (N*16*4 = 6.4 MB)   total 15.8 MB < E*4 = 25.6 MB
    unsigned int* flag = (unsigned int*)(ws + off_flag);

    if (ws_size >= need && (size_t)E * 4 >= 9 * 1024 * 1024 + (size_t)N * 64) {
        int* bin_start        = (int*)(ws + off_binstart);
        int* totals           = (int*)(ws + off_totals);
        int* rp               = (int*)(ws + off_rp);
        int* hist             = (int*)(ws + off_hist);
        int* off_rel          = (int*)(ws + off_offrel);
        float4* xp            = (float4*)(ws + off_xp);
        unsigned int* sorted1 = (unsigned int*)(ws + off_sorted1);
        unsigned int* sorted2 = (unsigned int*)(ws + off_sorted2);
        float* agg1 = (float*)(ws + off_sorted1);
        float* agg2 = (float*)(ws + off_sorted1 + 2 * 1024 * 1024);
        float* h    = (float*)(ws + off_sorted1 + 9 * 1024 * 1024);

        hipMemsetAsync(ws, 0, 4, stream);
        detect_i64_kernel<<<8, 256, 0, stream>>>((const unsigned int*)eidx, flag);
        pad_x_kernel<<<(N + 255) / 256, 256, 0, stream>>>(x, xp, N);
        count_kernel<<<NCHUNK, 256, 0, stream>>>(eidx, flag, hist, E);
        scan1_kernel<<<(NBINS_TOT * 64 + 511) / 512, 512, 0, stream>>>(hist, off_rel, totals);
        scan2_kernel<<<1, 1024, 0, stream>>>(totals, bin_start);
        scatter1_kernel<<<NCHUNK, 256, 0, stream>>>(eidx, flag, off_rel, bin_start, sorted1, E);
        dlsort_kernel<<<NBINS_TOT, 512, 0, stream>>>(sorted1, bin_start, sorted2, rp, N);

        agg5_csr<<<(4 * N + 255) / 256, 256, 0, stream>>>(sorted2, rp, xp, agg1, N);
        mlp1_kernel<<<(N + 255) / 256, 256, 0, stream>>>(x, agg1, W1a, b1a, W1b, b1b, h, N);
        agg16_csr<<<(4 * N + 255) / 256, 256, 0, stream>>>(sorted2, rp, (const float4*)h, agg2, N);
        mlp2_kernel<<<(N + 255) / 256, 256, 0, stream>>>(h, agg2, W2a, b2a, W2b, b2b, out, N);
    } else {
        // fallback: global-atomic path
        const size_t f_agg1 = 4096;
        const size_t f_agg2 = f_agg1 + 2 * 1024 * 1024;
        const size_t f_h    = f_agg2 + 7 * 1024 * 1024;
        float* agg1 = (float*)(ws + f_agg1);
        float* agg2 = (float*)(ws + f_agg2);
        float* h    = (float*)(ws + f_h);

        hipMemsetAsync(ws, 0, f_agg2 + (size_t)N * 16 * 4, stream);
        detect_i64_kernel<<<8, 256, 0, stream>>>((const unsigned int*)eidx, flag);
        int blocks = (E + 255) / 256;
        scatter_f5_kernel<<<blocks, 256, 0, stream>>>(eidx, flag, x, agg1, E);
        mlp1_kernel<<<(N + 255) / 256, 256, 0, stream>>>(x, agg1, W1a, b1a, W1b, b1b, h, N);
        scatter_f16_kernel<<<blocks, 256, 0, stream>>>(eidx, flag, h, agg2, E);
        mlp2_kernel<<<(N + 255) / 256, 256, 0, stream>>>(h, agg2, W2a, b2a, W2b, b2b, out, N);
    }
}

// Round 10
// 249.183 us; speedup vs baseline: 1.2866x; 1.2866x over previous
//
#include <hip/hip_runtime.h>

#define N_NODES 100000
#define NBIN_D  391           // dst bins of 256 nodes (391*256 = 100096)
#define NW      4             // src windows: src>>15
#define NBINS_TOT (NW * NBIN_D)   // 1564 sort bins, w-major
#define NCHUNK  512
#define CAP     8192          // LDS stage capacity (mean bin = 4096 edges)

// ---------------- dtype detection (int64 vs int32 edge_index) ---------------
// edge values < 2^31. If int64 LE, every odd 32-bit word is 0.
__global__ void detect_i64_kernel(const unsigned int* __restrict__ e,
                                  unsigned int* __restrict__ flag) {
    int i = blockIdx.x * blockDim.x + threadIdx.x;  // 0..2047
    unsigned int v = e[2 * i + 1];
    if (v != 0u) atomicOr(flag, 1u);
}

// ---------------- pad x (N x 5 f32) -> fp32x8 (32B rows) --------------------
__global__ void pad_x_kernel(const float* __restrict__ x, float4* __restrict__ xp, int N) {
    int n = blockIdx.x * blockDim.x + threadIdx.x;
    if (n >= N) return;
    const float* p = x + (long long)n * 5;
    xp[n * 2]     = make_float4(p[0], p[1], p[2], p[3]);
    xp[n * 2 + 1] = make_float4(p[4], 0.f, 0.f, 0.f);
}

// ---------------- pass 1a: per-chunk histogram over (w, dst_bin) ------------
__global__ void count_kernel(const void* __restrict__ eidx,
                             const unsigned int* __restrict__ flag,
                             int* __restrict__ hist, int E) {
    __shared__ int lh[NBINS_TOT];
    int tid = threadIdx.x, c = blockIdx.x;
    for (int i = tid; i < NBINS_TOT; i += blockDim.x) lh[i] = 0;
    __syncthreads();
    int per = (E + NCHUNK - 1) / NCHUNK;
    int e0 = c * per, e1 = min(E, e0 + per);
    unsigned int is32 = *flag;
    for (int e = e0 + tid; e < e1; e += blockDim.x) {
        int s, d;
        if (is32) {
            const int* p = (const int*)eidx; s = p[e]; d = p[E + e];
        } else {
            const long long* p = (const long long*)eidx; s = (int)p[e]; d = (int)p[E + e];
        }
        atomicAdd(&lh[(s >> 15) * NBIN_D + (d >> 8)], 1);
    }
    __syncthreads();
    for (int i = tid; i < NBINS_TOT; i += blockDim.x) hist[c * NBINS_TOT + i] = lh[i];
}

// ---------------- pass 1b: per-bin column scan (1 wave per bin) -------------
__global__ void scan1_kernel(const int* __restrict__ hist,
                             int* __restrict__ off_rel,
                             int* __restrict__ totals) {
    int gtid = blockIdx.x * blockDim.x + threadIdx.x;
    int b = gtid >> 6;
    int lane = threadIdx.x & 63;
    if (b >= NBINS_TOT) return;
    int carry = 0;
    for (int k = 0; k < NCHUNK; k += 64) {
        int v = hist[(k + lane) * NBINS_TOT + b];
        int sc = v;
        for (int off = 1; off < 64; off <<= 1) {
            int t = __shfl_up(sc, off);
            if (lane >= off) sc += t;
        }
        off_rel[(k + lane) * NBINS_TOT + b] = carry + sc - v;   // exclusive
        carry += __shfl(sc, 63);
    }
    if (lane == 0) totals[b] = carry;
}

// ---------------- pass 1c: scan bin totals -> bin_start (2 per thread) ------
__global__ void scan2_kernel(const int* __restrict__ totals,
                             int* __restrict__ bin_start) {
    __shared__ int buf[1024];
    int t = threadIdx.x;
    int i0 = 2 * t, i1 = 2 * t + 1;
    int v0 = (i0 < NBINS_TOT) ? totals[i0] : 0;
    int v1 = (i1 < NBINS_TOT) ? totals[i1] : 0;
    int s = v0 + v1;
    buf[t] = s;
    __syncthreads();
    for (int off = 1; off < 1024; off <<= 1) {
        int v = (t >= off) ? buf[t - off] : 0;
        __syncthreads();
        buf[t] += v;
        __syncthreads();
    }
    int excl = buf[t] - s;
    if (t == 0) bin_start[0] = 0;
    if (i0 < NBINS_TOT) bin_start[i0 + 1] = excl + v0;
    if (i1 < NBINS_TOT) bin_start[i1 + 1] = excl + v0 + v1;
}

// ---------------- pass 1d: scatter edges into (w, dst_bin) order ------------
// packed edge word: (dl << 17) | src   (dl = dst & 255, src < 2^17)
__global__ void scatter1_kernel(const void* __restrict__ eidx,
                                const unsigned int* __restrict__ flag,
                                const int* __restrict__ off_rel,
                                const int* __restrict__ bin_start,
                                unsigned int* __restrict__ sorted1, int E) {
    __shared__ int lcnt[NBINS_TOT];
    __shared__ int lbase[NBINS_TOT];
    int tid = threadIdx.x, c = blockIdx.x;
    for (int i = tid; i < NBINS_TOT; i += blockDim.x) {
        lcnt[i] = 0;
        lbase[i] = bin_start[i] + off_rel[c * NBINS_TOT + i];
    }
    __syncthreads();
    int per = (E + NCHUNK - 1) / NCHUNK;
    int e0 = c * per, e1 = min(E, e0 + per);
    unsigned int is32 = *flag;
    for (int e = e0 + tid; e < e1; e += blockDim.x) {
        int s, d;
        if (is32) {
            const int* p = (const int*)eidx; s = p[e]; d = p[E + e];
        } else {
            const long long* p = (const long long*)eidx; s = (int)p[e]; d = (int)p[E + e];
        }
        int b = (s >> 15) * NBIN_D + (d >> 8);
        int dl = d & 255;
        int pos = lbase[b] + atomicAdd(&lcnt[b], 1);
        sorted1[pos] = ((unsigned int)dl << 17) | (unsigned int)s;
    }
}

// ---------------- pass 2: per-(w,bin) LDS counting sort -> window CSR -------
// rp[w*(N+1) + n] .. rp[w*(N+1) + n + 1] = node n's edges in window w.
__global__ __launch_bounds__(512) void dlsort_kernel(
    const unsigned int* __restrict__ sorted1,
    const int* __restrict__ bin_start,
    unsigned int* __restrict__ sorted2,
    int* __restrict__ rp, int N) {
    __shared__ int hist[256];
    __shared__ int pfx[256];
    __shared__ int offc[256];
    __shared__ unsigned int stage[CAP];
    int tid = threadIdx.x, b = blockIdx.x;
    int w = b / NBIN_D, dbin = b - w * NBIN_D;
    int bs = bin_start[b], be = bin_start[b + 1];
    int cnt = be - bs;
    if (tid < 256) hist[tid] = 0;
    __syncthreads();
    for (int e = bs + tid; e < be; e += 512)
        atomicAdd(&hist[(sorted1[e] >> 17) & 255], 1);
    __syncthreads();
    if (tid < 256) pfx[tid] = hist[tid];
    __syncthreads();
    for (int off = 1; off < 256; off <<= 1) {
        int v = (tid < 256 && tid >= off) ? pfx[tid - off] : 0;
        __syncthreads();
        if (tid < 256) pfx[tid] += v;
        __syncthreads();
    }
    if (tid < 256) {
        int excl = pfx[tid] - hist[tid];
        offc[tid] = excl;
        int node = dbin * 256 + tid;
        if (node <= N) rp[w * (N + 1) + node] = bs + excl;
    }
    __syncthreads();
    if (cnt <= CAP) {
        for (int e = bs + tid; e < be; e += 512) {
            unsigned int wd = sorted1[e];
            int pos = atomicAdd(&offc[(wd >> 17) & 255], 1);
            stage[pos] = wd;
        }
        __syncthreads();
        for (int i = tid; i < cnt; i += 512) sorted2[bs + i] = stage[i];
    } else {
        // overflow slow path (statistically unreachable for uniform dst)
        for (int e = bs + tid; e < be; e += 512) {
            unsigned int wd = sorted1[e];
            int pos = bs + atomicAdd(&offc[(wd >> 17) & 255], 1);
            sorted2[pos] = wd;
        }
    }
}

// ------- aggregation F=5 (layer 1): 2 lanes/node (edge parity), serial w ----
__global__ __launch_bounds__(256) void agg5_csr(
    const unsigned int* __restrict__ sorted2, const int* __restrict__ rp,
    const float4* __restrict__ xp, float* __restrict__ agg, int N) {
    int t = blockIdx.x * 256 + threadIdx.x;
    int n = t >> 1, q = t & 1;
    if (n >= N) return;
    float a0 = 0, a1 = 0, a2 = 0, a3 = 0, a4 = 0;
#pragma unroll
    for (int w = 0; w < NW; ++w) {
        int e0 = rp[w * (N + 1) + n], e1 = rp[w * (N + 1) + n + 1];
        for (int e = e0 + q; e < e1; e += 2) {
            int s0 = (int)(sorted2[e] & 0x1FFFF);
            float4 v0 = xp[s0 * 2], w0 = xp[s0 * 2 + 1];
            a0 += v0.x; a1 += v0.y; a2 += v0.z; a3 += v0.w; a4 += w0.x;
        }
    }
    // combine the two edge-parity lanes
    a0 += __shfl_xor(a0, 1); a1 += __shfl_xor(a1, 1); a2 += __shfl_xor(a2, 1);
    a3 += __shfl_xor(a3, 1); a4 += __shfl_xor(a4, 1);
    if (q == 0) {
        float* o = agg + (long long)n * 5;
        o[0] = a0; o[1] = a1; o[2] = a2; o[3] = a3; o[4] = a4;
    }
}

// ------- aggregation F=16 (layer 2): 4 lanes/node (feature quad), serial w --
// Lanes q=0..3 of a node read h[s*4+q] -> one contiguous 64B line per edge.
__global__ __launch_bounds__(256) void agg16_csr(
    const unsigned int* __restrict__ sorted2, const int* __restrict__ rp,
    const float4* __restrict__ h, float* __restrict__ agg, int N) {
    int t = blockIdx.x * 256 + threadIdx.x;
    int n = t >> 2, q = t & 3;
    if (n >= N) return;
    float a0 = 0, a1 = 0, a2 = 0, a3 = 0;
#pragma unroll
    for (int w = 0; w < NW; ++w) {
        int e0 = rp[w * (N + 1) + n], e1 = rp[w * (N + 1) + n + 1];
        int e = e0;
        for (; e + 1 < e1; e += 2) {
            int s0 = (int)(sorted2[e] & 0x1FFFF), s1 = (int)(sorted2[e + 1] & 0x1FFFF);
            float4 v0 = h[s0 * 4 + q];
            float4 v1 = h[s1 * 4 + q];
            a0 += v0.x; a1 += v0.y; a2 += v0.z; a3 += v0.w;
            a0 += v1.x; a1 += v1.y; a2 += v1.z; a3 += v1.w;
        }
        if (e < e1) {
            int s0 = (int)(sorted2[e] & 0x1FFFF);
            float4 v0 = h[s0 * 4 + q];
            a0 += v0.x; a1 += v0.y; a2 += v0.z; a3 += v0.w;
        }
    }
    float4* o = (float4*)(agg + (long long)n * 16);
    o[q] = make_float4(a0, a1, a2, a3);
}

// ------------- MLP1: h = relu((x+agg1)@W1a+b1a)@W1b+b1b  (fp32 h) -----------
__global__ void mlp1_kernel(const float* __restrict__ x,
                            const float* __restrict__ agg,
                            const float* __restrict__ W1, const float* __restrict__ b1,
                            const float* __restrict__ W2, const float* __restrict__ b2,
                            float* __restrict__ h, int N) {
    int n = blockIdx.x * blockDim.x + threadIdx.x;
    if (n >= N) return;
    float in[5];
#pragma unroll
    for (int f = 0; f < 5; ++f)
        in[f] = x[(long long)n * 5 + f] + agg[(long long)n * 5 + f];
    float hid[16];
#pragma unroll
    for (int j = 0; j < 16; ++j) {
        float acc = b1[j];
#pragma unroll
        for (int f = 0; f < 5; ++f) acc = fmaf(in[f], W1[f * 16 + j], acc);
        hid[j] = fmaxf(acc, 0.0f);
    }
    float4* op = (float4*)(h + (long long)n * 16);
#pragma unroll
    for (int jq = 0; jq < 4; ++jq) {
        float4 v;
        float acc;
        acc = b2[jq * 4 + 0];
#pragma unroll
        for (int k = 0; k < 16; ++k) acc = fmaf(hid[k], W2[k * 16 + jq * 4 + 0], acc);
        v.x = acc;
        acc = b2[jq * 4 + 1];
#pragma unroll
        for (int k = 0; k < 16; ++k) acc = fmaf(hid[k], W2[k * 16 + jq * 4 + 1], acc);
        v.y = acc;
        acc = b2[jq * 4 + 2];
#pragma unroll
        for (int k = 0; k < 16; ++k) acc = fmaf(hid[k], W2[k * 16 + jq * 4 + 2], acc);
        v.z = acc;
        acc = b2[jq * 4 + 3];
#pragma unroll
        for (int k = 0; k < 16; ++k) acc = fmaf(hid[k], W2[k * 16 + jq * 4 + 3], acc);
        v.w = acc;
        op[jq] = v;
    }
}

// ------------- MLP2: out = relu((h+agg2)@W2a+b2a)@W2b+b2b -------------------
__global__ void mlp2_kernel(const float* __restrict__ h,
                            const float* __restrict__ agg,
                            const float* __restrict__ W1, const float* __restrict__ b1,
                            const float* __restrict__ W2, const float* __restrict__ b2,
                            float* __restrict__ out, int N) {
    int n = blockIdx.x * blockDim.x + threadIdx.x;
    if (n >= N) return;
    float in[16];
    const float4* hp = (const float4*)(h + (long long)n * 16);
    const float4* ap = (const float4*)(agg + (long long)n * 16);
#pragma unroll
    for (int qq = 0; qq < 4; ++qq) {
        float4 a = hp[qq], b = ap[qq];
        in[qq * 4 + 0] = a.x + b.x; in[qq * 4 + 1] = a.y + b.y;
        in[qq * 4 + 2] = a.z + b.z; in[qq * 4 + 3] = a.w + b.w;
    }
    float hid[16];
#pragma unroll
    for (int j = 0; j < 16; ++j) {
        float acc = b1[j];
#pragma unroll
        for (int f = 0; f < 16; ++f) acc = fmaf(in[f], W1[f * 16 + j], acc);
        hid[j] = fmaxf(acc, 0.0f);
    }
    float4* op = (float4*)(out + (long long)n * 16);
#pragma unroll
    for (int jq = 0; jq < 4; ++jq) {
        float4 v;
        float acc;
        acc = b2[jq * 4 + 0];
#pragma unroll
        for (int k = 0; k < 16; ++k) acc = fmaf(hid[k], W2[k * 16 + jq * 4 + 0], acc);
        v.x = acc;
        acc = b2[jq * 4 + 1];
#pragma unroll
        for (int k = 0; k < 16; ++k) acc = fmaf(hid[k], W2[k * 16 + jq * 4 + 1], acc);
        v.y = acc;
        acc = b2[jq * 4 + 2];
#pragma unroll
        for (int k = 0; k < 16; ++k) acc = fmaf(hid[k], W2[k * 16 + jq * 4 + 2], acc);
        v.z = acc;
        acc = b2[jq * 4 + 3];
#pragma unroll
        for (int k = 0; k < 16; ++k) acc = fmaf(hid[k], W2[k * 16 + jq * 4 + 3], acc);
        v.w = acc;
        op[jq] = v;
    }
}

// ---------- fallback path (ws too small): global atomics, fp32 --------------
__device__ __forceinline__ void load_edge(const void* eidx, unsigned int is32,
                                          int i, int E, int& s, int& d) {
    if (is32 == 0u) {
        const long long* p = (const long long*)eidx;
        s = (int)p[i]; d = (int)p[E + i];
    } else {
        const int* p = (const int*)eidx;
        s = p[i]; d = p[E + i];
    }
}

__global__ void scatter_f5_kernel(const void* __restrict__ eidx,
                                  const unsigned int* __restrict__ flag,
                                  const float* __restrict__ x,
                                  float* __restrict__ agg, int E) {
    int i = blockIdx.x * blockDim.x + threadIdx.x;
    if (i >= E) return;
    int s, d; load_edge(eidx, *flag, i, E, s, d);
    const float* xs = x + (long long)s * 5;
    float* a = agg + (long long)d * 5;
#pragma unroll
    for (int f = 0; f < 5; ++f) atomicAdd(&a[f], xs[f]);
}

__global__ void scatter_f16_kernel(const void* __restrict__ eidx,
                                   const unsigned int* __restrict__ flag,
                                   const float* __restrict__ h,
                                   float* __restrict__ agg, int E) {
    int i = blockIdx.x * blockDim.x + threadIdx.x;
    if (i >= E) return;
    int s, d; load_edge(eidx, *flag, i, E, s, d);
    const float* hs = h + (long long)s * 16;
    float* a = agg + (long long)d * 16;
#pragma unroll
    for (int f = 0; f < 16; ++f) atomicAdd(&a[f], hs[f]);
}

extern "C" void kernel_launch(void* const* d_in, const int* in_sizes, int n_in,
                              void* d_out, int out_size, void* d_ws, size_t ws_size,
                              hipStream_t stream) {
    const float* x    = (const float*)d_in[0];
    const void*  eidx = d_in[1];
    const float* W1a  = (const float*)d_in[2];
    const float* b1a  = (const float*)d_in[3];
    const float* W1b  = (const float*)d_in[4];
    const float* b1b  = (const float*)d_in[5];
    const float* W2a  = (const float*)d_in[6];
    const float* b2a  = (const float*)d_in[7];
    const float* W2b  = (const float*)d_in[8];
    const float* b2b  = (const float*)d_in[9];
    float* out = (float*)d_out;

    const int E = in_sizes[1] / 2;
    const int N = N_NODES;

    char* ws = (char*)d_ws;
    auto align256 = [](size_t v) { return (v + 255) & ~(size_t)255; };
    const size_t hist_bytes = (size_t)NCHUNK * NBINS_TOT * 4;          // 3.2 MB

    const size_t off_flag     = 0;
    const size_t off_binstart = 256;                                    // 1565*4
    const size_t off_totals   = align256(off_binstart + (NBINS_TOT + 1) * 4);
    const size_t off_rp       = align256(off_totals + NBINS_TOT * 4);   // NW*(N+1)*4
    const size_t off_hist     = align256(off_rp + (size_t)NW * (N + 1) * 4);
    const size_t off_offrel   = align256(off_hist + hist_bytes);
    const size_t off_xp       = align256(off_offrel + hist_bytes);      // N*32 fp32x8
    const size_t off_sorted1  = align256(off_xp + (size_t)N * 32);      // E*4
    const size_t off_sorted2  = align256(off_sorted1 + (size_t)E * 4);  // E*4
    const size_t need         = off_sorted2 + (size_t)E * 4;

    // agg1/agg2/h alias the dead sorted1 region after dlsort:
    //   agg1 @ +0        (N*5*4  = 2.0 MB)
    //   agg2 @ +2 MiB    (N*16*4 = 6.4 MB)
    //   h    @ +9 MiB    (N*16*4 = 6.4 MB)   total 15.8 MB < E*4 = 25.6 MB
    unsigned int* flag = (unsigned int*)(ws + off_flag);

    if (ws_size >= need && (size_t)E * 4 >= 9 * 1024 * 1024 + (size_t)N * 64) {
        int* bin_start        = (int*)(ws + off_binstart);
        int* totals           = (int*)(ws + off_totals);
        int* rp               = (int*)(ws + off_rp);
        int* hist             = (int*)(ws + off_hist);
        int* off_rel          = (int*)(ws + off_offrel);
        float4* xp            = (float4*)(ws + off_xp);
        unsigned int* sorted1 = (unsigned int*)(ws + off_sorted1);
        unsigned int* sorted2 = (unsigned int*)(ws + off_sorted2);
        float* agg1 = (float*)(ws + off_sorted1);
        float* agg2 = (float*)(ws + off_sorted1 + 2 * 1024 * 1024);
        float* h    = (float*)(ws + off_sorted1 + 9 * 1024 * 1024);

        hipMemsetAsync(ws, 0, 4, stream);
        detect_i64_kernel<<<8, 256, 0, stream>>>((const unsigned int*)eidx, flag);
        pad_x_kernel<<<(N + 255) / 256, 256, 0, stream>>>(x, xp, N);
        count_kernel<<<NCHUNK, 256, 0, stream>>>(eidx, flag, hist, E);
        scan1_kernel<<<(NBINS_TOT * 64 + 511) / 512, 512, 0, stream>>>(hist, off_rel, totals);
        scan2_kernel<<<1, 1024, 0, stream>>>(totals, bin_start);
        scatter1_kernel<<<NCHUNK, 256, 0, stream>>>(eidx, flag, off_rel, bin_start, sorted1, E);
        dlsort_kernel<<<NBINS_TOT, 512, 0, stream>>>(sorted1, bin_start, sorted2, rp, N);

        agg5_csr<<<(2 * N + 255) / 256, 256, 0, stream>>>(sorted2, rp, xp, agg1, N);
        mlp1_kernel<<<(N + 255) / 256, 256, 0, stream>>>(x, agg1, W1a, b1a, W1b, b1b, h, N);
        agg16_csr<<<(4 * N + 255) / 256, 256, 0, stream>>>(sorted2, rp, (const float4*)h, agg2, N);
        mlp2_kernel<<<(N + 255) / 256, 256, 0, stream>>>(h, agg2, W2a, b2a, W2b, b2b, out, N);
    } else {
        // fallback: global-atomic path
        const size_t f_agg1 = 4096;
        const size_t f_agg2 = f_agg1 + 2 * 1024 * 1024;
        const size_t f_h    = f_agg2 + 7 * 1024 * 1024;
        float* agg1 = (float*)(ws + f_agg1);
        float* agg2 = (float*)(ws + f_agg2);
        float* h    = (float*)(ws + f_h);

        hipMemsetAsync(ws, 0, f_agg2 + (size_t)N * 16 * 4, stream);
        detect_i64_kernel<<<8, 256, 0, stream>>>((const unsigned int*)eidx, flag);
        int blocks = (E + 255) / 256;
        scatter_f5_kernel<<<blocks, 256, 0, stream>>>(eidx, flag, x, agg1, E);
        mlp1_kernel<<<(N + 255) / 256, 256, 0, stream>>>(x, agg1, W1a, b1a, W1b, b1b, h, N);
        scatter_f16_kernel<<<blocks, 256, 0, stream>>>(eidx, flag, h, agg2, E);
        mlp2_kernel<<<(N + 255) / 256, 256, 0, stream>>>(h, agg2, W2a, b2a, W2b, b2b, out, N);
    }
}

// Round 11
// 247.912 us; speedup vs baseline: 1.2932x; 1.0051x over previous
//
#include <hip/hip_runtime.h>

#define N_NODES 100000
#define NBIN_D  196           // dst bins of 512 nodes (196*512 = 100352)
#define NW      4             // src windows: src>>15
#define NBINS_TOT (NW * NBIN_D)   // 784 sort bins, w-major
#define NCHUNK  256
#define CAP     10240         // LDS stage capacity (mean bin = 8163 edges)

// ---------------- dtype detection (int64 vs int32 edge_index) ---------------
// edge values < 2^31. If int64 LE, every odd 32-bit word is 0.
__global__ void detect_i64_kernel(const unsigned int* __restrict__ e,
                                  unsigned int* __restrict__ flag) {
    int i = blockIdx.x * blockDim.x + threadIdx.x;  // 0..2047
    unsigned int v = e[2 * i + 1];
    if (v != 0u) atomicOr(flag, 1u);
}

// ---------------- pad x (N x 5 f32) -> fp32x8 (32B rows) --------------------
__global__ void pad_x_kernel(const float* __restrict__ x, float4* __restrict__ xp, int N) {
    int n = blockIdx.x * blockDim.x + threadIdx.x;
    if (n >= N) return;
    const float* p = x + (long long)n * 5;
    xp[n * 2]     = make_float4(p[0], p[1], p[2], p[3]);
    xp[n * 2 + 1] = make_float4(p[4], 0.f, 0.f, 0.f);
}

// ---------------- pass 1a: per-chunk histogram over (w, dst_bin) ------------
__global__ __launch_bounds__(1024) void count_kernel(
    const void* __restrict__ eidx, const unsigned int* __restrict__ flag,
    int* __restrict__ hist, int E) {
    __shared__ int lh[NBINS_TOT];
    int tid = threadIdx.x, c = blockIdx.x;
    for (int i = tid; i < NBINS_TOT; i += 1024) lh[i] = 0;
    __syncthreads();
    int per = (E + NCHUNK - 1) / NCHUNK;
    int e0 = c * per, e1 = min(E, e0 + per);
    unsigned int is32 = *flag;
    for (int e = e0 + tid; e < e1; e += 1024) {
        int s, d;
        if (is32) {
            const int* p = (const int*)eidx; s = p[e]; d = p[E + e];
        } else {
            const long long* p = (const long long*)eidx; s = (int)p[e]; d = (int)p[E + e];
        }
        atomicAdd(&lh[(s >> 15) * NBIN_D + (d >> 9)], 1);
    }
    __syncthreads();
    for (int i = tid; i < NBINS_TOT; i += 1024) hist[c * NBINS_TOT + i] = lh[i];
}

// ---------------- pass 1b: per-bin column scan (1 wave per bin) -------------
__global__ void scan1_kernel(const int* __restrict__ hist,
                             int* __restrict__ off_rel,
                             int* __restrict__ totals) {
    int gtid = blockIdx.x * blockDim.x + threadIdx.x;
    int b = gtid >> 6;
    int lane = threadIdx.x & 63;
    if (b >= NBINS_TOT) return;
    int carry = 0;
    for (int k = 0; k < NCHUNK; k += 64) {
        int v = hist[(k + lane) * NBINS_TOT + b];
        int sc = v;
        for (int off = 1; off < 64; off <<= 1) {
            int t = __shfl_up(sc, off);
            if (lane >= off) sc += t;
        }
        off_rel[(k + lane) * NBINS_TOT + b] = carry + sc - v;   // exclusive
        carry += __shfl(sc, 63);
    }
    if (lane == 0) totals[b] = carry;
}

// ---------------- pass 1c: scan bin totals -> bin_start ---------------------
__global__ void scan2_kernel(const int* __restrict__ totals,
                             int* __restrict__ bin_start) {
    __shared__ int buf[1024];
    int tid = threadIdx.x;
    buf[tid] = (tid < NBINS_TOT) ? totals[tid] : 0;
    __syncthreads();
    for (int off = 1; off < 1024; off <<= 1) {
        int v = (tid >= off) ? buf[tid - off] : 0;
        __syncthreads();
        buf[tid] += v;
        __syncthreads();
    }
    if (tid < NBINS_TOT) bin_start[tid + 1] = buf[tid];
    if (tid == 0) bin_start[0] = 0;
}

// ---------------- pass 1d: scatter edges into (w, dst_bin) order ------------
// packed edge word: (dl << 17) | src   (dl = dst & 511, src < 2^17)
__global__ __launch_bounds__(1024) void scatter1_kernel(
    const void* __restrict__ eidx, const unsigned int* __restrict__ flag,
    const int* __restrict__ off_rel, const int* __restrict__ bin_start,
    unsigned int* __restrict__ sorted1, int E) {
    __shared__ int lcnt[NBINS_TOT];
    __shared__ int lbase[NBINS_TOT];
    int tid = threadIdx.x, c = blockIdx.x;
    for (int i = tid; i < NBINS_TOT; i += 1024) {
        lcnt[i] = 0;
        lbase[i] = bin_start[i] + off_rel[c * NBINS_TOT + i];
    }
    __syncthreads();
    int per = (E + NCHUNK - 1) / NCHUNK;
    int e0 = c * per, e1 = min(E, e0 + per);
    unsigned int is32 = *flag;
    for (int e = e0 + tid; e < e1; e += 1024) {
        int s, d;
        if (is32) {
            const int* p = (const int*)eidx; s = p[e]; d = p[E + e];
        } else {
            const long long* p = (const long long*)eidx; s = (int)p[e]; d = (int)p[E + e];
        }
        int b = (s >> 15) * NBIN_D + (d >> 9);
        int dl = d & 511;
        int pos = lbase[b] + atomicAdd(&lcnt[b], 1);
        sorted1[pos] = ((unsigned int)dl << 17) | (unsigned int)s;
    }
}

// ---------------- pass 2: per-(w,bin) LDS counting sort -> window CSR -------
// rp[w*(N+1) + n] .. rp[w*(N+1) + n + 1] = node n's edges in window w.
__global__ __launch_bounds__(512) void dlsort_kernel(
    const unsigned int* __restrict__ sorted1,
    const int* __restrict__ bin_start,
    unsigned int* __restrict__ sorted2,
    int* __restrict__ rp, int N) {
    __shared__ int hist[512];
    __shared__ int pfx[512];
    __shared__ int offc[512];
    __shared__ unsigned int stage[CAP];
    int tid = threadIdx.x, b = blockIdx.x;
    int w = b / NBIN_D, dbin = b - w * NBIN_D;
    int bs = bin_start[b], be = bin_start[b + 1];
    int cnt = be - bs;
    hist[tid] = 0;
    __syncthreads();
    for (int e = bs + tid; e < be; e += 512)
        atomicAdd(&hist[(sorted1[e] >> 17) & 511], 1);
    __syncthreads();
    pfx[tid] = hist[tid];
    __syncthreads();
    for (int off = 1; off < 512; off <<= 1) {
        int v = (tid >= off) ? pfx[tid - off] : 0;
        __syncthreads();
        pfx[tid] += v;
        __syncthreads();
    }
    {
        int excl = pfx[tid] - hist[tid];
        offc[tid] = excl;
        int node = dbin * 512 + tid;
        if (node <= N) rp[w * (N + 1) + node] = bs + excl;
    }
    __syncthreads();
    if (cnt <= CAP) {
        for (int e = bs + tid; e < be; e += 512) {
            unsigned int wd = sorted1[e];
            int pos = atomicAdd(&offc[(wd >> 17) & 511], 1);
            stage[pos] = wd;
        }
        __syncthreads();
        for (int i = tid; i < cnt; i += 512) sorted2[bs + i] = stage[i];
    } else {
        // overflow slow path (statistically unreachable for uniform dst)
        for (int e = bs + tid; e < be; e += 512) {
            unsigned int wd = sorted1[e];
            int pos = bs + atomicAdd(&offc[(wd >> 17) & 511], 1);
            sorted2[pos] = wd;
        }
    }
}

// ------- aggregation F=5 (layer 1): 2 lanes/node (edge parity), serial w ----
__global__ __launch_bounds__(256) void agg5_csr(
    const unsigned int* __restrict__ sorted2, const int* __restrict__ rp,
    const float4* __restrict__ xp, float* __restrict__ agg, int N) {
    int t = blockIdx.x * 256 + threadIdx.x;
    int n = t >> 1, q = t & 1;
    if (n >= N) return;
    float a0 = 0, a1 = 0, a2 = 0, a3 = 0, a4 = 0;
#pragma unroll
    for (int w = 0; w < NW; ++w) {
        int e0 = rp[w * (N + 1) + n], e1 = rp[w * (N + 1) + n + 1];
        for (int e = e0 + q; e < e1; e += 2) {
            int s0 = (int)(sorted2[e] & 0x1FFFF);
            float4 v0 = xp[s0 * 2], w0 = xp[s0 * 2 + 1];
            a0 += v0.x; a1 += v0.y; a2 += v0.z; a3 += v0.w; a4 += w0.x;
        }
    }
    a0 += __shfl_xor(a0, 1); a1 += __shfl_xor(a1, 1); a2 += __shfl_xor(a2, 1);
    a3 += __shfl_xor(a3, 1); a4 += __shfl_xor(a4, 1);
    if (q == 0) {
        float* o = agg + (long long)n * 5;
        o[0] = a0; o[1] = a1; o[2] = a2; o[3] = a3; o[4] = a4;
    }
}

// ------- aggregation F=16 (layer 2): 4 lanes/node (feature quad), serial w --
__global__ __launch_bounds__(256) void agg16_csr(
    const unsigned int* __restrict__ sorted2, const int* __restrict__ rp,
    const float4* __restrict__ h, float* __restrict__ agg, int N) {
    int t = blockIdx.x * 256 + threadIdx.x;
    int n = t >> 2, q = t & 3;
    if (n >= N) return;
    float a0 = 0, a1 = 0, a2 = 0, a3 = 0;
#pragma unroll
    for (int w = 0; w < NW; ++w) {
        int e0 = rp[w * (N + 1) + n], e1 = rp[w * (N + 1) + n + 1];
        int e = e0;
        for (; e + 1 < e1; e += 2) {
            int s0 = (int)(sorted2[e] & 0x1FFFF), s1 = (int)(sorted2[e + 1] & 0x1FFFF);
            float4 v0 = h[s0 * 4 + q];
            float4 v1 = h[s1 * 4 + q];
            a0 += v0.x; a1 += v0.y; a2 += v0.z; a3 += v0.w;
            a0 += v1.x; a1 += v1.y; a2 += v1.z; a3 += v1.w;
        }
        if (e < e1) {
            int s0 = (int)(sorted2[e] & 0x1FFFF);
            float4 v0 = h[s0 * 4 + q];
            a0 += v0.x; a1 += v0.y; a2 += v0.z; a3 += v0.w;
        }
    }
    float4* o = (float4*)(agg + (long long)n * 16);
    o[q] = make_float4(a0, a1, a2, a3);
}

// ------------- MLP1: h = relu((x+agg1)@W1a+b1a)@W1b+b1b  (fp32 h) -----------
__global__ void mlp1_kernel(const float* __restrict__ x,
                            const float* __restrict__ agg,
                            const float* __restrict__ W1, const float* __restrict__ b1,
                            const float* __restrict__ W2, const float* __restrict__ b2,
                            float* __restrict__ h, int N) {
    int n = blockIdx.x * blockDim.x + threadIdx.x;
    if (n >= N) return;
    float in[5];
#pragma unroll
    for (int f = 0; f < 5; ++f)
        in[f] = x[(long long)n * 5 + f] + agg[(long long)n * 5 + f];
    float hid[16];
#pragma unroll
    for (int j = 0; j < 16; ++j) {
        float acc = b1[j];
#pragma unroll
        for (int f = 0; f < 5; ++f) acc = fmaf(in[f], W1[f * 16 + j], acc);
        hid[j] = fmaxf(acc, 0.0f);
    }
    float4* op = (float4*)(h + (long long)n * 16);
#pragma unroll
    for (int jq = 0; jq < 4; ++jq) {
        float4 v;
        float acc;
        acc = b2[jq * 4 + 0];
#pragma unroll
        for (int k = 0; k < 16; ++k) acc = fmaf(hid[k], W2[k * 16 + jq * 4 + 0], acc);
        v.x = acc;
        acc = b2[jq * 4 + 1];
#pragma unroll
        for (int k = 0; k < 16; ++k) acc = fmaf(hid[k], W2[k * 16 + jq * 4 + 1], acc);
        v.y = acc;
        acc = b2[jq * 4 + 2];
#pragma unroll
        for (int k = 0; k < 16; ++k) acc = fmaf(hid[k], W2[k * 16 + jq * 4 + 2], acc);
        v.z = acc;
        acc = b2[jq * 4 + 3];
#pragma unroll
        for (int k = 0; k < 16; ++k) acc = fmaf(hid[k], W2[k * 16 + jq * 4 + 3], acc);
        v.w = acc;
        op[jq] = v;
    }
}

// ------------- MLP2: out = relu((h+agg2)@W2a+b2a)@W2b+b2b -------------------
__global__ void mlp2_kernel(const float* __restrict__ h,
                            const float* __restrict__ agg,
                            const float* __restrict__ W1, const float* __restrict__ b1,
                            const float* __restrict__ W2, const float* __restrict__ b2,
                            float* __restrict__ out, int N) {
    int n = blockIdx.x * blockDim.x + threadIdx.x;
    if (n >= N) return;
    float in[16];
    const float4* hp = (const float4*)(h + (long long)n * 16);
    const float4* ap = (const float4*)(agg + (long long)n * 16);
#pragma unroll
    for (int qq = 0; qq < 4; ++qq) {
        float4 a = hp[qq], b = ap[qq];
        in[qq * 4 + 0] = a.x + b.x; in[qq * 4 + 1] = a.y + b.y;
        in[qq * 4 + 2] = a.z + b.z; in[qq * 4 + 3] = a.w + b.w;
    }
    float hid[16];
#pragma unroll
    for (int j = 0; j < 16; ++j) {
        float acc = b1[j];
#pragma unroll
        for (int f = 0; f < 16; ++f) acc = fmaf(in[f], W1[f * 16 + j], acc);
        hid[j] = fmaxf(acc, 0.0f);
    }
    float4* op = (float4*)(out + (long long)n * 16);
#pragma unroll
    for (int jq = 0; jq < 4; ++jq) {
        float4 v;
        float acc;
        acc = b2[jq * 4 + 0];
#pragma unroll
        for (int k = 0; k < 16; ++k) acc = fmaf(hid[k], W2[k * 16 + jq * 4 + 0], acc);
        v.x = acc;
        acc = b2[jq * 4 + 1];
#pragma unroll
        for (int k = 0; k < 16; ++k) acc = fmaf(hid[k], W2[k * 16 + jq * 4 + 1], acc);
        v.y = acc;
        acc = b2[jq * 4 + 2];
#pragma unroll
        for (int k = 0; k < 16; ++k) acc = fmaf(hid[k], W2[k * 16 + jq * 4 + 2], acc);
        v.z = acc;
        acc = b2[jq * 4 + 3];
#pragma unroll
        for (int k = 0; k < 16; ++k) acc = fmaf(hid[k], W2[k * 16 + jq * 4 + 3], acc);
        v.w = acc;
        op[jq] = v;
    }
}

// ---------- fallback path (ws too small): global atomics, fp32 --------------
__device__ __forceinline__ void load_edge(const void* eidx, unsigned int is32,
                                          int i, int E, int& s, int& d) {
    if (is32 == 0u) {
        const long long* p = (const long long*)eidx;
        s = (int)p[i]; d = (int)p[E + i];
    } else {
        const int* p = (const int*)eidx;
        s = p[i]; d = p[E + i];
    }
}

__global__ void scatter_f5_kernel(const void* __restrict__ eidx,
                                  const unsigned int* __restrict__ flag,
                                  const float* __restrict__ x,
                                  float* __restrict__ agg, int E) {
    int i = blockIdx.x * blockDim.x + threadIdx.x;
    if (i >= E) return;
    int s, d; load_edge(eidx, *flag, i, E, s, d);
    const float* xs = x + (long long)s * 5;
    float* a = agg + (long long)d * 5;
#pragma unroll
    for (int f = 0; f < 5; ++f) atomicAdd(&a[f], xs[f]);
}

__global__ void scatter_f16_kernel(const void* __restrict__ eidx,
                                   const unsigned int* __restrict__ flag,
                                   const float* __restrict__ h,
                                   float* __restrict__ agg, int E) {
    int i = blockIdx.x * blockDim.x + threadIdx.x;
    if (i >= E) return;
    int s, d; load_edge(eidx, *flag, i, E, s, d);
    const float* hs = h + (long long)s * 16;
    float* a = agg + (long long)d * 16;
#pragma unroll
    for (int f = 0; f < 16; ++f) atomicAdd(&a[f], hs[f]);
}

extern "C" void kernel_launch(void* const* d_in, const int* in_sizes, int n_in,
                              void* d_out, int out_size, void* d_ws, size_t ws_size,
                              hipStream_t stream) {
    const float* x    = (const float*)d_in[0];
    const void*  eidx = d_in[1];
    const float* W1a  = (const float*)d_in[2];
    const float* b1a  = (const float*)d_in[3];
    const float* W1b  = (const float*)d_in[4];
    const float* b1b  = (const float*)d_in[5];
    const float* W2a  = (const float*)d_in[6];
    const float* b2a  = (const float*)d_in[7];
    const float* W2b  = (const float*)d_in[8];
    const float* b2b  = (const float*)d_in[9];
    float* out = (float*)d_out;

    const int E = in_sizes[1] / 2;
    const int N = N_NODES;

    char* ws = (char*)d_ws;
    auto align256 = [](size_t v) { return (v + 255) & ~(size_t)255; };
    const size_t hist_bytes = (size_t)NCHUNK * NBINS_TOT * 4;          // 802,816

    const size_t off_flag     = 0;
    const size_t off_binstart = 256;                                    // 785*4
    const size_t off_totals   = align256(off_binstart + (NBINS_TOT + 1) * 4);
    const size_t off_rp       = align256(off_totals + NBINS_TOT * 4);   // NW*(N+1)*4
    const size_t off_hist     = align256(off_rp + (size_t)NW * (N + 1) * 4);
    const size_t off_offrel   = align256(off_hist + hist_bytes);
    const size_t off_xp       = align256(off_offrel + hist_bytes);      // N*32 fp32x8
    const size_t off_sorted1  = align256(off_xp + (size_t)N * 32);      // E*4
    const size_t off_sorted2  = align256(off_sorted1 + (size_t)E * 4);  // E*4
    const size_t need         = off_sorted2 + (size_t)E * 4;

    // agg1/agg2/h alias the dead sorted1 region after dlsort:
    //   agg1 @ +0        (N*5*4  = 2.0 MB)
    //   agg2 @ +2 MiB    (N*16*4 = 6.4 MB)
    //   h    @ +9 MiB    (N*16*4 = 6.4 MB)   total 15.8 MB < E*4 = 25.6 MB
    unsigned int* flag = (unsigned int*)(ws + off_flag);

    if (ws_size >= need && (size_t)E * 4 >= 9 * 1024 * 1024 + (size_t)N * 64) {
        int* bin_start        = (int*)(ws + off_binstart);
        int* totals           = (int*)(ws + off_totals);
        int* rp               = (int*)(ws + off_rp);
        int* hist             = (int*)(ws + off_hist);
        int* off_rel          = (int*)(ws + off_offrel);
        float4* xp            = (float4*)(ws + off_xp);
        unsigned int* sorted1 = (unsigned int*)(ws + off_sorted1);
        unsigned int* sorted2 = (unsigned int*)(ws + off_sorted2);
        float* agg1 = (float*)(ws + off_sorted1);
        float* agg2 = (float*)(ws + off_sorted1 + 2 * 1024 * 1024);
        float* h    = (float*)(ws + off_sorted1 + 9 * 1024 * 1024);

        hipMemsetAsync(ws, 0, 4, stream);
        detect_i64_kernel<<<8, 256, 0, stream>>>((const unsigned int*)eidx, flag);
        pad_x_kernel<<<(N + 255) / 256, 256, 0, stream>>>(x, xp, N);
        count_kernel<<<NCHUNK, 1024, 0, stream>>>(eidx, flag, hist, E);
        scan1_kernel<<<(NBINS_TOT * 64 + 511) / 512, 512, 0, stream>>>(hist, off_rel, totals);
        scan2_kernel<<<1, 1024, 0, stream>>>(totals, bin_start);
        scatter1_kernel<<<NCHUNK, 1024, 0, stream>>>(eidx, flag, off_rel, bin_start, sorted1, E);
        dlsort_kernel<<<NBINS_TOT, 512, 0, stream>>>(sorted1, bin_start, sorted2, rp, N);

        agg5_csr<<<(2 * N + 255) / 256, 256, 0, stream>>>(sorted2, rp, xp, agg1, N);
        mlp1_kernel<<<(N + 255) / 256, 256, 0, stream>>>(x, agg1, W1a, b1a, W1b, b1b, h, N);
        agg16_csr<<<(4 * N + 255) / 256, 256, 0, stream>>>(sorted2, rp, (const float4*)h, agg2, N);
        mlp2_kernel<<<(N + 255) / 256, 256, 0, stream>>>(h, agg2, W2a, b2a, W2b, b2b, out, N);
    } else {
        // fallback: global-atomic path
        const size_t f_agg1 = 4096;
        const size_t f_agg2 = f_agg1 + 2 * 1024 * 1024;
        const size_t f_h    = f_agg2 + 7 * 1024 * 1024;
        float* agg1 = (float*)(ws + f_agg1);
        float* agg2 = (float*)(ws + f_agg2);
        float* h    = (float*)(ws + f_h);

        hipMemsetAsync(ws, 0, f_agg2 + (size_t)N * 16 * 4, stream);
        detect_i64_kernel<<<8, 256, 0, stream>>>((const unsigned int*)eidx, flag);
        int blocks = (E + 255) / 256;
        scatter_f5_kernel<<<blocks, 256, 0, stream>>>(eidx, flag, x, agg1, E);
        mlp1_kernel<<<(N + 255) / 256, 256, 0, stream>>>(x, agg1, W1a, b1a, W1b, b1b, h, N);
        scatter_f16_kernel<<<blocks, 256, 0, stream>>>(eidx, flag, h, agg2, E);
        mlp2_kernel<<<(N + 255) / 256, 256, 0, stream>>>(h, agg2, W2a, b2a, W2b, b2b, out, N);
    }
}

// Round 12
// 208.330 us; speedup vs baseline: 1.5389x; 1.1900x over previous
//
#include <hip/hip_runtime.h>

#define N_NODES 100000
#define NBIN_D  196           // dst bins of 512 nodes (196*512 = 100352)
#define NW      4             // src windows of 25000 nodes (uniform!)
#define WSPAN   25000
#define NBINS_TOT (NW * NBIN_D)   // 784 sort bins, w-major
#define NCHUNK  256
#define CAP     12032         // LDS stage capacity (mean bin = 8163, +43 sigma)

// ---------------- dtype detection (int64 vs int32 edge_index) ---------------
// edge values < 2^31. If int64 LE, every odd 32-bit word is 0.
__global__ void detect_i64_kernel(const unsigned int* __restrict__ e,
                                  unsigned int* __restrict__ flag) {
    int i = blockIdx.x * blockDim.x + threadIdx.x;  // 0..2047
    unsigned int v = e[2 * i + 1];
    if (v != 0u) atomicOr(flag, 1u);
}

// ---------------- pad x (N x 5 f32) -> fp32x8 (32B rows) --------------------
__global__ void pad_x_kernel(const float* __restrict__ x, float4* __restrict__ xp, int N) {
    int n = blockIdx.x * blockDim.x + threadIdx.x;
    if (n >= N) return;
    const float* p = x + (long long)n * 5;
    xp[n * 2]     = make_float4(p[0], p[1], p[2], p[3]);
    xp[n * 2 + 1] = make_float4(p[4], 0.f, 0.f, 0.f);
}

// ---------------- pass 1a: per-chunk histogram over (w, dst_bin) ------------
__global__ __launch_bounds__(1024) void count_kernel(
    const void* __restrict__ eidx, const unsigned int* __restrict__ flag,
    int* __restrict__ hist, int E) {
    __shared__ int lh[NBINS_TOT];
    int tid = threadIdx.x, c = blockIdx.x;
    for (int i = tid; i < NBINS_TOT; i += 1024) lh[i] = 0;
    __syncthreads();
    int per = (E + NCHUNK - 1) / NCHUNK;
    int e0 = c * per, e1 = min(E, e0 + per);
    unsigned int is32 = *flag;
    for (int e = e0 + tid; e < e1; e += 1024) {
        int s, d;
        if (is32) {
            const int* p = (const int*)eidx; s = p[e]; d = p[E + e];
        } else {
            const long long* p = (const long long*)eidx; s = (int)p[e]; d = (int)p[E + e];
        }
        atomicAdd(&lh[(s / WSPAN) * NBIN_D + (d >> 9)], 1);
    }
    __syncthreads();
    for (int i = tid; i < NBINS_TOT; i += 1024) hist[c * NBINS_TOT + i] = lh[i];
}

// ---------------- pass 1b: per-bin column scan (1 wave per bin) -------------
__global__ void scan1_kernel(const int* __restrict__ hist,
                             int* __restrict__ off_rel,
                             int* __restrict__ totals) {
    int gtid = blockIdx.x * blockDim.x + threadIdx.x;
    int b = gtid >> 6;
    int lane = threadIdx.x & 63;
    if (b >= NBINS_TOT) return;
    int carry = 0;
    for (int k = 0; k < NCHUNK; k += 64) {
        int v = hist[(k + lane) * NBINS_TOT + b];
        int sc = v;
        for (int off = 1; off < 64; off <<= 1) {
            int t = __shfl_up(sc, off);
            if (lane >= off) sc += t;
        }
        off_rel[(k + lane) * NBINS_TOT + b] = carry + sc - v;   // exclusive
        carry += __shfl(sc, 63);
    }
    if (lane == 0) totals[b] = carry;
}

// ---------------- pass 1c: scan bin totals -> bin_start ---------------------
__global__ void scan2_kernel(const int* __restrict__ totals,
                             int* __restrict__ bin_start) {
    __shared__ int buf[1024];
    int tid = threadIdx.x;
    buf[tid] = (tid < NBINS_TOT) ? totals[tid] : 0;
    __syncthreads();
    for (int off = 1; off < 1024; off <<= 1) {
        int v = (tid >= off) ? buf[tid - off] : 0;
        __syncthreads();
        buf[tid] += v;
        __syncthreads();
    }
    if (tid < NBINS_TOT) bin_start[tid + 1] = buf[tid];
    if (tid == 0) bin_start[0] = 0;
}

// ---------------- pass 1d: scatter edges into (w, dst_bin) order ------------
// packed edge word: (dl << 17) | src   (dl = dst & 511, src < 2^17)
__global__ __launch_bounds__(1024) void scatter1_kernel(
    const void* __restrict__ eidx, const unsigned int* __restrict__ flag,
    const int* __restrict__ off_rel, const int* __restrict__ bin_start,
    unsigned int* __restrict__ sorted1, int E) {
    __shared__ int lcnt[NBINS_TOT];
    __shared__ int lbase[NBINS_TOT];
    int tid = threadIdx.x, c = blockIdx.x;
    for (int i = tid; i < NBINS_TOT; i += 1024) {
        lcnt[i] = 0;
        lbase[i] = bin_start[i] + off_rel[c * NBINS_TOT + i];
    }
    __syncthreads();
    int per = (E + NCHUNK - 1) / NCHUNK;
    int e0 = c * per, e1 = min(E, e0 + per);
    unsigned int is32 = *flag;
    for (int e = e0 + tid; e < e1; e += 1024) {
        int s, d;
        if (is32) {
            const int* p = (const int*)eidx; s = p[e]; d = p[E + e];
        } else {
            const long long* p = (const long long*)eidx; s = (int)p[e]; d = (int)p[E + e];
        }
        int b = (s / WSPAN) * NBIN_D + (d >> 9);
        int dl = d & 511;
        int pos = lbase[b] + atomicAdd(&lcnt[b], 1);
        sorted1[pos] = ((unsigned int)dl << 17) | (unsigned int)s;
    }
}

// ---------------- pass 2: per-(w,bin) LDS counting sort -> window CSR -------
// rp[w*(N+1) + n] .. rp[w*(N+1) + n + 1] = node n's edges in window w.
__global__ __launch_bounds__(512) void dlsort_kernel(
    const unsigned int* __restrict__ sorted1,
    const int* __restrict__ bin_start,
    unsigned int* __restrict__ sorted2,
    int* __restrict__ rp, int N) {
    __shared__ int hist[512];
    __shared__ int pfx[512];
    __shared__ int offc[512];
    __shared__ unsigned int stage[CAP];
    int tid = threadIdx.x, b = blockIdx.x;
    int w = b / NBIN_D, dbin = b - w * NBIN_D;
    int bs = bin_start[b], be = bin_start[b + 1];
    int cnt = be - bs;
    hist[tid] = 0;
    __syncthreads();
    for (int e = bs + tid; e < be; e += 512)
        atomicAdd(&hist[(sorted1[e] >> 17) & 511], 1);
    __syncthreads();
    pfx[tid] = hist[tid];
    __syncthreads();
    for (int off = 1; off < 512; off <<= 1) {
        int v = (tid >= off) ? pfx[tid - off] : 0;
        __syncthreads();
        pfx[tid] += v;
        __syncthreads();
    }
    {
        int excl = pfx[tid] - hist[tid];
        offc[tid] = excl;
        int node = dbin * 512 + tid;
        if (node <= N) rp[w * (N + 1) + node] = bs + excl;
    }
    __syncthreads();
    if (cnt <= CAP) {
        for (int e = bs + tid; e < be; e += 512) {
            unsigned int wd = sorted1[e];
            int pos = atomicAdd(&offc[(wd >> 17) & 511], 1);
            stage[pos] = wd;
        }
        __syncthreads();
        for (int i = tid; i < cnt; i += 512) sorted2[bs + i] = stage[i];
    } else {
        // overflow slow path (safety net; unreachable for uniform dst/src)
        for (int e = bs + tid; e < be; e += 512) {
            unsigned int wd = sorted1[e];
            int pos = bs + atomicAdd(&offc[(wd >> 17) & 511], 1);
            sorted2[pos] = wd;
        }
    }
}

// ------- aggregation F=5 (layer 1): 2 lanes/node (edge parity), serial w ----
__global__ __launch_bounds__(256) void agg5_csr(
    const unsigned int* __restrict__ sorted2, const int* __restrict__ rp,
    const float4* __restrict__ xp, float* __restrict__ agg, int N) {
    int t = blockIdx.x * 256 + threadIdx.x;
    int n = t >> 1, q = t & 1;
    if (n >= N) return;
    float a0 = 0, a1 = 0, a2 = 0, a3 = 0, a4 = 0;
#pragma unroll
    for (int w = 0; w < NW; ++w) {
        int e0 = rp[w * (N + 1) + n], e1 = rp[w * (N + 1) + n + 1];
        for (int e = e0 + q; e < e1; e += 2) {
            int s0 = (int)(sorted2[e] & 0x1FFFF);
            float4 v0 = xp[s0 * 2], w0 = xp[s0 * 2 + 1];
            a0 += v0.x; a1 += v0.y; a2 += v0.z; a3 += v0.w; a4 += w0.x;
        }
    }
    a0 += __shfl_xor(a0, 1); a1 += __shfl_xor(a1, 1); a2 += __shfl_xor(a2, 1);
    a3 += __shfl_xor(a3, 1); a4 += __shfl_xor(a4, 1);
    if (q == 0) {
        float* o = agg + (long long)n * 5;
        o[0] = a0; o[1] = a1; o[2] = a2; o[3] = a3; o[4] = a4;
    }
}

// ------- aggregation F=16 (layer 2): 4 lanes/node (feature quad), serial w --
__global__ __launch_bounds__(256) void agg16_csr(
    const unsigned int* __restrict__ sorted2, const int* __restrict__ rp,
    const float4* __restrict__ h, float* __restrict__ agg, int N) {
    int t = blockIdx.x * 256 + threadIdx.x;
    int n = t >> 2, q = t & 3;
    if (n >= N) return;
    float a0 = 0, a1 = 0, a2 = 0, a3 = 0;
#pragma unroll
    for (int w = 0; w < NW; ++w) {
        int e0 = rp[w * (N + 1) + n], e1 = rp[w * (N + 1) + n + 1];
        int e = e0;
        for (; e + 1 < e1; e += 2) {
            int s0 = (int)(sorted2[e] & 0x1FFFF), s1 = (int)(sorted2[e + 1] & 0x1FFFF);
            float4 v0 = h[s0 * 4 + q];
            float4 v1 = h[s1 * 4 + q];
            a0 += v0.x; a1 += v0.y; a2 += v0.z; a3 += v0.w;
            a0 += v1.x; a1 += v1.y; a2 += v1.z; a3 += v1.w;
        }
        if (e < e1) {
            int s0 = (int)(sorted2[e] & 0x1FFFF);
            float4 v0 = h[s0 * 4 + q];
            a0 += v0.x; a1 += v0.y; a2 += v0.z; a3 += v0.w;
        }
    }
    float4* o = (float4*)(agg + (long long)n * 16);
    o[q] = make_float4(a0, a1, a2, a3);
}

// ------------- MLP1: h = relu((x+agg1)@W1a+b1a)@W1b+b1b  (fp32 h) -----------
__global__ void mlp1_kernel(const float* __restrict__ x,
                            const float* __restrict__ agg,
                            const float* __restrict__ W1, const float* __restrict__ b1,
                            const float* __restrict__ W2, const float* __restrict__ b2,
                            float* __restrict__ h, int N) {
    int n = blockIdx.x * blockDim.x + threadIdx.x;
    if (n >= N) return;
    float in[5];
#pragma unroll
    for (int f = 0; f < 5; ++f)
        in[f] = x[(long long)n * 5 + f] + agg[(long long)n * 5 + f];
    float hid[16];
#pragma unroll
    for (int j = 0; j < 16; ++j) {
        float acc = b1[j];
#pragma unroll
        for (int f = 0; f < 5; ++f) acc = fmaf(in[f], W1[f * 16 + j], acc);
        hid[j] = fmaxf(acc, 0.0f);
    }
    float4* op = (float4*)(h + (long long)n * 16);
#pragma unroll
    for (int jq = 0; jq < 4; ++jq) {
        float4 v;
        float acc;
        acc = b2[jq * 4 + 0];
#pragma unroll
        for (int k = 0; k < 16; ++k) acc = fmaf(hid[k], W2[k * 16 + jq * 4 + 0], acc);
        v.x = acc;
        acc = b2[jq * 4 + 1];
#pragma unroll
        for (int k = 0; k < 16; ++k) acc = fmaf(hid[k], W2[k * 16 + jq * 4 + 1], acc);
        v.y = acc;
        acc = b2[jq * 4 + 2];
#pragma unroll
        for (int k = 0; k < 16; ++k) acc = fmaf(hid[k], W2[k * 16 + jq * 4 + 2], acc);
        v.z = acc;
        acc = b2[jq * 4 + 3];
#pragma unroll
        for (int k = 0; k < 16; ++k) acc = fmaf(hid[k], W2[k * 16 + jq * 4 + 3], acc);
        v.w = acc;
        op[jq] = v;
    }
}

// ------------- MLP2: out = relu((h+agg2)@W2a+b2a)@W2b+b2b -------------------
__global__ void mlp2_kernel(const float* __restrict__ h,
                            const float* __restrict__ agg,
                            const float* __restrict__ W1, const float* __restrict__ b1,
                            const float* __restrict__ W2, const float* __restrict__ b2,
                            float* __restrict__ out, int N) {
    int n = blockIdx.x * blockDim.x + threadIdx.x;
    if (n >= N) return;
    float in[16];
    const float4* hp = (const float4*)(h + (long long)n * 16);
    const float4* ap = (const float4*)(agg + (long long)n * 16);
#pragma unroll
    for (int qq = 0; qq < 4; ++qq) {
        float4 a = hp[qq], b = ap[qq];
        in[qq * 4 + 0] = a.x + b.x; in[qq * 4 + 1] = a.y + b.y;
        in[qq * 4 + 2] = a.z + b.z; in[qq * 4 + 3] = a.w + b.w;
    }
    float hid[16];
#pragma unroll
    for (int j = 0; j < 16; ++j) {
        float acc = b1[j];
#pragma unroll
        for (int f = 0; f < 16; ++f) acc = fmaf(in[f], W1[f * 16 + j], acc);
        hid[j] = fmaxf(acc, 0.0f);
    }
    float4* op = (float4*)(out + (long long)n * 16);
#pragma unroll
    for (int jq = 0; jq < 4; ++jq) {
        float4 v;
        float acc;
        acc = b2[jq * 4 + 0];
#pragma unroll
        for (int k = 0; k < 16; ++k) acc = fmaf(hid[k], W2[k * 16 + jq * 4 + 0], acc);
        v.x = acc;
        acc = b2[jq * 4 + 1];
#pragma unroll
        for (int k = 0; k < 16; ++k) acc = fmaf(hid[k], W2[k * 16 + jq * 4 + 1], acc);
        v.y = acc;
        acc = b2[jq * 4 + 2];
#pragma unroll
        for (int k = 0; k < 16; ++k) acc = fmaf(hid[k], W2[k * 16 + jq * 4 + 2], acc);
        v.z = acc;
        acc = b2[jq * 4 + 3];
#pragma unroll
        for (int k = 0; k < 16; ++k) acc = fmaf(hid[k], W2[k * 16 + jq * 4 + 3], acc);
        v.w = acc;
        op[jq] = v;
    }
}

// ---------- fallback path (ws too small): global atomics, fp32 --------------
__device__ __forceinline__ void load_edge(const void* eidx, unsigned int is32,
                                          int i, int E, int& s, int& d) {
    if (is32 == 0u) {
        const long long* p = (const long long*)eidx;
        s = (int)p[i]; d = (int)p[E + i];
    } else {
        const int* p = (const int*)eidx;
        s = p[i]; d = p[E + i];
    }
}

__global__ void scatter_f5_kernel(const void* __restrict__ eidx,
                                  const unsigned int* __restrict__ flag,
                                  const float* __restrict__ x,
                                  float* __restrict__ agg, int E) {
    int i = blockIdx.x * blockDim.x + threadIdx.x;
    if (i >= E) return;
    int s, d; load_edge(eidx, *flag, i, E, s, d);
    const float* xs = x + (long long)s * 5;
    float* a = agg + (long long)d * 5;
#pragma unroll
    for (int f = 0; f < 5; ++f) atomicAdd(&a[f], xs[f]);
}

__global__ void scatter_f16_kernel(const void* __restrict__ eidx,
                                   const unsigned int* __restrict__ flag,
                                   const float* __restrict__ h,
                                   float* __restrict__ agg, int E) {
    int i = blockIdx.x * blockDim.x + threadIdx.x;
    if (i >= E) return;
    int s, d; load_edge(eidx, *flag, i, E, s, d);
    const float* hs = h + (long long)s * 16;
    float* a = agg + (long long)d * 16;
#pragma unroll
    for (int f = 0; f < 16; ++f) atomicAdd(&a[f], hs[f]);
}

extern "C" void kernel_launch(void* const* d_in, const int* in_sizes, int n_in,
                              void* d_out, int out_size, void* d_ws, size_t ws_size,
                              hipStream_t stream) {
    const float* x    = (const float*)d_in[0];
    const void*  eidx = d_in[1];
    const float* W1a  = (const float*)d_in[2];
    const float* b1a  = (const float*)d_in[3];
    const float* W1b  = (const float*)d_in[4];
    const float* b1b  = (const float*)d_in[5];
    const float* W2a  = (const float*)d_in[6];
    const float* b2a  = (const float*)d_in[7];
    const float* W2b  = (const float*)d_in[8];
    const float* b2b  = (const float*)d_in[9];
    float* out = (float*)d_out;

    const int E = in_sizes[1] / 2;
    const int N = N_NODES;

    char* ws = (char*)d_ws;
    auto align256 = [](size_t v) { return (v + 255) & ~(size_t)255; };
    const size_t hist_bytes = (size_t)NCHUNK * NBINS_TOT * 4;          // 802,816

    const size_t off_flag     = 0;
    const size_t off_binstart = 256;                                    // 785*4
    const size_t off_totals   = align256(off_binstart + (NBINS_TOT + 1) * 4);
    const size_t off_rp       = align256(off_totals + NBINS_TOT * 4);   // NW*(N+1)*4
    const size_t off_hist     = align256(off_rp + (size_t)NW * (N + 1) * 4);
    const size_t off_offrel   = align256(off_hist + hist_bytes);
    const size_t off_xp       = align256(off_offrel + hist_bytes);      // N*32 fp32x8
    const size_t off_sorted1  = align256(off_xp + (size_t)N * 32);      // E*4
    const size_t off_sorted2  = align256(off_sorted1 + (size_t)E * 4);  // E*4
    const size_t need         = off_sorted2 + (size_t)E * 4;

    // agg1/agg2/h alias the dead sorted1 region after dlsort:
    //   agg1 @ +0        (N*5*4  = 2.0 MB)
    //   agg2 @ +2 MiB    (N*16*4 = 6.4 MB)
    //   h    @ +9 MiB    (N*16*4 = 6.4 MB)   total 15.8 MB < E*4 = 25.6 MB
    unsigned int* flag = (unsigned int*)(ws + off_flag);

    if (ws_size >= need && (size_t)E * 4 >= 9 * 1024 * 1024 + (size_t)N * 64) {
        int* bin_start        = (int*)(ws + off_binstart);
        int* totals           = (int*)(ws + off_totals);
        int* rp               = (int*)(ws + off_rp);
        int* hist             = (int*)(ws + off_hist);
        int* off_rel          = (int*)(ws + off_offrel);
        float4* xp            = (float4*)(ws + off_xp);
        unsigned int* sorted1 = (unsigned int*)(ws + off_sorted1);
        unsigned int* sorted2 = (unsigned int*)(ws + off_sorted2);
        float* agg1 = (float*)(ws + off_sorted1);
        float* agg2 = (float*)(ws + off_sorted1 + 2 * 1024 * 1024);
        float* h    = (float*)(ws + off_sorted1 + 9 * 1024 * 1024);

        hipMemsetAsync(ws, 0, 4, stream);
        detect_i64_kernel<<<8, 256, 0, stream>>>((const unsigned int*)eidx, flag);
        pad_x_kernel<<<(N + 255) / 256, 256, 0, stream>>>(x, xp, N);
        count_kernel<<<NCHUNK, 1024, 0, stream>>>(eidx, flag, hist, E);
        scan1_kernel<<<(NBINS_TOT * 64 + 511) / 512, 512, 0, stream>>>(hist, off_rel, totals);
        scan2_kernel<<<1, 1024, 0, stream>>>(totals, bin_start);
        scatter1_kernel<<<NCHUNK, 1024, 0, stream>>>(eidx, flag, off_rel, bin_start, sorted1, E);
        dlsort_kernel<<<NBINS_TOT, 512, 0, stream>>>(sorted1, bin_start, sorted2, rp, N);

        agg5_csr<<<(2 * N + 255) / 256, 256, 0, stream>>>(sorted2, rp, xp, agg1, N);
        mlp1_kernel<<<(N + 255) / 256, 256, 0, stream>>>(x, agg1, W1a, b1a, W1b, b1b, h, N);
        agg16_csr<<<(4 * N + 255) / 256, 256, 0, stream>>>(sorted2, rp, (const float4*)h, agg2, N);
        mlp2_kernel<<<(N + 255) / 256, 256, 0, stream>>>(h, agg2, W2a, b2a, W2b, b2b, out, N);
    } else {
        // fallback: global-atomic path
        const size_t f_agg1 = 4096;
        const size_t f_agg2 = f_agg1 + 2 * 1024 * 1024;
        const size_t f_h    = f_agg2 + 7 * 1024 * 1024;
        float* agg1 = (float*)(ws + f_agg1);
        float* agg2 = (float*)(ws + f_agg2);
        float* h    = (float*)(ws + f_h);

        hipMemsetAsync(ws, 0, f_agg2 + (size_t)N * 16 * 4, stream);
        detect_i64_kernel<<<8, 256, 0, stream>>>((const unsigned int*)eidx, flag);
        int blocks = (E + 255) / 256;
        scatter_f5_kernel<<<blocks, 256, 0, stream>>>(eidx, flag, x, agg1, E);
        mlp1_kernel<<<(N + 255) / 256, 256, 0, stream>>>(x, agg1, W1a, b1a, W1b, b1b, h, N);
        scatter_f16_kernel<<<blocks, 256, 0, stream>>>(eidx, flag, h, agg2, E);
        mlp2_kernel<<<(N + 255) / 256, 256, 0, stream>>>(h, agg2, W2a, b2a, W2b, b2b, out, N);
    }
}